// Round 3
// baseline (193.877 us; speedup 1.0000x reference)
//
#include <hip/hip_runtime.h>
#include <math.h>

// Problem dims
#define NB 64
#define NA 23
#define NT 128
#define ND 256
#define NAE 32
#define NS 6
#define NH 8
#define NDM 288
#define NBA (NB*NA)   // 1472

// Workspace layout (float offsets). Total 4,663,944 floats = 18.66 MB.
#define OFF_PK     0           // PK[j][t] = sum_e pe[t][e]*Wk[e][j]*scale : 256*128
#define OFF_PET    32768       // peT[e][t] : 256*128
#define OFF_WKT    65536       // WkTs[j][e] = Wk[e][j]*scale : 256*256
#define OFF_VWO    131072      // VWo[h][e] : 8*288
#define OFF_QBIAS  133376      // qbias[a][j] = bq[j] + E_var[a].Wq[256:,j] : 23*256
#define OFF_CST    139264      // [0..5]=W_static.Wg1, [6]=b_static.Wg1+bg, [7]=bo.Wg0, [8..15]=bv-part
#define OFF_EVV    139280      // evv[a][h] : 23*8
#define OFF_PEM    139464      // peM[h][t] = pe @ VWo : 8*128
#define OFF_QK     140488      // qk[ba][h][e] : 1472*2048
#define OFF_PES    3155144     // peS[ba][h][t] : 1472*1024
#define OFF_S      4662472     // s[ba] : 1472

#define KDIV  0.07195578415606394f    // ln(10000)/128
#define KSCALE 0.17677669529663687f   // 1/sqrt(32)

// ---------------- setup1: 416 blocks ----------------
//  [0,128)   : t-blocks — pe row (1 transcendental/thread), peT, PK[j][t]
//  [128,384) : WkTs transpose rows
//  [384,392) : per-head VWo (redundant WoWg slice)
//  [392,415) : qbias[a][:]
//  [415]     : cst[0..15] (incl. WoWg-based bv part)
__global__ __launch_bounds__(256) void setup1_kernel(
    const float* __restrict__ Wk, const float* __restrict__ Wq,
    const float* __restrict__ bq, const float* __restrict__ E_var,
    const float* __restrict__ Wv, const float* __restrict__ Wo,
    const float* __restrict__ Wg, const float* __restrict__ bv,
    const float* __restrict__ bo, const float* __restrict__ W_static,
    const float* __restrict__ b_static, const float* __restrict__ bg,
    float* __restrict__ ws)
{
    const int blk = blockIdx.x, tid = threadIdx.x;
    __shared__ float sm[256];
    if (blk < 128) {
        const int t = blk;
        const int e = tid, i = e >> 1;
        const float dv = __expf(-(float)i * KDIV);
        const float ang = (float)t * dv;
        const float v = (e & 1) ? cosf(ang) : sinf(ang);
        sm[e] = v;
        ws[OFF_PET + e * NT + t] = v;
        __syncthreads();
        float acc = 0.f;
        #pragma unroll 4
        for (int e2 = 0; e2 < 256; ++e2)
            acc = fmaf(sm[e2], Wk[e2 * ND + tid], acc);
        ws[OFF_PK + tid * NT + t] = acc * KSCALE;
    } else if (blk < 384) {
        const int j = blk - 128;
        ws[OFF_WKT + j * 256 + tid] = Wk[tid * ND + j] * KSCALE;
    } else if (blk < 392) {
        const int h = blk - 384;
        __shared__ float wog[32];
        {
            const int jj = tid >> 3, sub = tid & 7;
            const int j = h * 32 + jj;
            float acc = 0.f;
            const int m0 = sub * 36;
            #pragma unroll 4
            for (int m = m0; m < m0 + 36; ++m)
                acc = fmaf(Wo[j * NDM + m], Wg[m], acc);
            acc += __shfl_down(acc, 4, 8);
            acc += __shfl_down(acc, 2, 8);
            acc += __shfl_down(acc, 1, 8);
            if (sub == 0) wog[jj] = acc;
        }
        __syncthreads();
        for (int e = tid; e < NDM; e += 256) {
            float acc = 0.f;
            #pragma unroll 8
            for (int jj = 0; jj < 32; ++jj)
                acc = fmaf(Wv[e * ND + h * 32 + jj], wog[jj], acc);
            ws[OFF_VWO + h * NDM + e] = acc;
        }
    } else if (blk < 415) {
        const int a = blk - 392;
        float acc = bq[tid];
        #pragma unroll 8
        for (int ee = 0; ee < NAE; ++ee)
            acc = fmaf(E_var[a * NAE + ee], Wq[(256 + ee) * ND + tid], acc);
        ws[OFF_QBIAS + a * ND + tid] = acc;
    } else {
        // WoWg into sm
        float acc = 0.f;
        const float* row = Wo + tid * NDM;
        for (int m = 0; m < NDM; ++m) acc = fmaf(row[m], Wg[m], acc);
        sm[tid] = acc;
        __syncthreads();
        const int i = tid >> 5, sub = tid & 31;
        float v = 0.f;
        if (i < 6) { for (int m = sub; m < 256; m += 32) v = fmaf(W_static[i * ND + m], Wg[NDM + m], v); }
        else if (i == 6) { for (int m = sub; m < 256; m += 32) v = fmaf(b_static[m], Wg[NDM + m], v); }
        else { for (int m = sub; m < NDM; m += 32) v = fmaf(bo[m], Wg[m], v); }
        #pragma unroll
        for (int off = 16; off > 0; off >>= 1) v += __shfl_down(v, off, 32);
        if (sub == 0) ws[OFF_CST + i] = (i == 6) ? v + bg[0] : v;
        {
            const int h = i, jj = sub;
            float u = bv[h * 32 + jj] * sm[h * 32 + jj];
            #pragma unroll
            for (int off = 16; off > 0; off >>= 1) u += __shfl_down(u, off, 32);
            if (sub == 0) ws[OFF_CST + 8 + h] = u;
        }
    }
}

// ---------------- proj: 373 blocks ----------------
//  [0,368)   : 4-ba tiles — agw (closed-form pe cumsum), q, qk, peS
//  [368,372) : peM[h][t] (2 h per block)
//  [372]     : evv[a][h]
__global__ __launch_bounds__(256) void proj_kernel(
    const float* __restrict__ data, const int* __restrict__ lengths,
    const float* __restrict__ W_embed, const float* __restrict__ b_embed,
    const float* __restrict__ E_var, const float* __restrict__ Wq,
    float* ws)
{
    const int blk = blockIdx.x, tid = threadIdx.x;
    if (blk < 368) {
        __shared__ __align__(16) float sm[4608];  // 18 KB
        float*  X    = sm;                       // [4][128]
        float2* Wb4  = (float2*)(sm + 512);      // [4][256]
        float*  agwS = sm + 512 + 2048;          // [f][4]
        float*  qS   = agwS + 1024;              // [j][4]
        const int wg4 = blk * 4;
        int aa[4], La[4];
        #pragma unroll
        for (int i = 0; i < 4; ++i) { aa[i] = (wg4 + i) % NA; La[i] = lengths[wg4 + i]; }
        if (tid < 128) {
            #pragma unroll
            for (int i = 0; i < 4; ++i) X[i * 128 + tid] = data[(wg4 + i) * NT + tid];
        }
        #pragma unroll
        for (int i = 0; i < 4; ++i)
            Wb4[i * 256 + tid] = make_float2(W_embed[aa[i] * ND + tid], b_embed[aa[i] * ND + tid]);
        __syncthreads();
        // agw (relu sum over t<L + closed-form pe cumsum) / L
        {
            const int e = tid;
            const int ii = e >> 1;
            const float dv = __expf(-(float)ii * KDIV);
            const float hd = 0.5f * dv;
            float agw[4];
            #pragma unroll
            for (int i = 0; i < 4; ++i) {
                const float2 wb = Wb4[i * 256 + e];
                const int Li = La[i];
                float acc = 0.f;
                #pragma unroll 4
                for (int t = 0; t < Li; ++t)
                    acc += fmaxf(fmaf(X[i * 128 + t], wb.x, wb.y), 0.f);
                float r = 0.f;
                if (Li > 0) {
                    // sum_{t<L} sin(t d) = sin((L-1)d/2) sin(Ld/2)/sin(d/2); cos analog
                    const float s1 = sinf((float)Li * hd);
                    const float a2 = (float)(Li - 1) * hd;
                    const float num = (e & 1) ? cosf(a2) : sinf(a2);
                    const float pec = num * s1 / sinf(hd);
                    r = (acc + pec) / (float)Li;
                }
                agw[i] = r;
            }
            *(float4*)&agwS[e * 4] = make_float4(agw[0], agw[1], agw[2], agw[3]);
        }
        __syncthreads();
        // q[j] for 4 ba
        {
            const int j = tid;
            float4 acc = make_float4(ws[OFF_QBIAS + aa[0] * ND + j], ws[OFF_QBIAS + aa[1] * ND + j],
                                     ws[OFF_QBIAS + aa[2] * ND + j], ws[OFF_QBIAS + aa[3] * ND + j]);
            #pragma unroll 4
            for (int f = 0; f < 256; ++f) {
                const float w = Wq[f * ND + j];
                const float4 ag = *(const float4*)&agwS[f * 4];
                acc.x = fmaf(ag.x, w, acc.x); acc.y = fmaf(ag.y, w, acc.y);
                acc.z = fmaf(ag.z, w, acc.z); acc.w = fmaf(ag.w, w, acc.w);
            }
            *(float4*)&qS[j * 4] = acc;
        }
        __syncthreads();
        // qk[e][h] for 4 ba
        {
            const int e = tid;
            for (int h = 0; h < 8; ++h) {
                float4 acc = make_float4(0.f, 0.f, 0.f, 0.f);
                #pragma unroll 8
                for (int j = 0; j < 32; ++j) {
                    const int jj = h * 32 + j;
                    const float w = ws[OFF_WKT + jj * 256 + e];
                    const float4 qv = *(const float4*)&qS[jj * 4];
                    acc.x = fmaf(qv.x, w, acc.x); acc.y = fmaf(qv.y, w, acc.y);
                    acc.z = fmaf(qv.z, w, acc.z); acc.w = fmaf(qv.w, w, acc.w);
                }
                ws[OFF_QK + (size_t)(wg4 + 0) * 2048 + h * 256 + e] = acc.x;
                ws[OFF_QK + (size_t)(wg4 + 1) * 2048 + h * 256 + e] = acc.y;
                ws[OFF_QK + (size_t)(wg4 + 2) * 2048 + h * 256 + e] = acc.z;
                ws[OFF_QK + (size_t)(wg4 + 3) * 2048 + h * 256 + e] = acc.w;
            }
        }
        // peS[ba][h][t] = sum_j q[j] * PK[j][t]
        {
            const int t = tid & 127, hg = tid >> 7;
            float accS[4][4];
            #pragma unroll
            for (int p = 0; p < 4; ++p)
                #pragma unroll
                for (int i = 0; i < 4; ++i) accS[p][i] = 0.f;
            #pragma unroll
            for (int p = 0; p < 4; ++p) {
                const int h = hg * 4 + p;
                #pragma unroll 4
                for (int j = 0; j < 32; ++j) {
                    const int jj = h * 32 + j;
                    const float pk = ws[OFF_PK + jj * NT + t];
                    const float4 qv = *(const float4*)&qS[jj * 4];
                    accS[p][0] = fmaf(qv.x, pk, accS[p][0]);
                    accS[p][1] = fmaf(qv.y, pk, accS[p][1]);
                    accS[p][2] = fmaf(qv.z, pk, accS[p][2]);
                    accS[p][3] = fmaf(qv.w, pk, accS[p][3]);
                }
            }
            #pragma unroll
            for (int p = 0; p < 4; ++p) {
                const int h = hg * 4 + p;
                #pragma unroll
                for (int i = 0; i < 4; ++i)
                    ws[OFF_PES + (size_t)(wg4 + i) * 1024 + h * 128 + t] = accS[p][i];
            }
        }
    } else if (blk < 372) {
        const int h = (blk - 368) * 2 + (tid >> 7);
        const int t = tid & 127;
        float acc = 0.f;
        #pragma unroll 4
        for (int e = 0; e < 256; ++e)
            acc = fmaf(ws[OFF_PET + e * NT + t], ws[OFF_VWO + h * NDM + e], acc);
        ws[OFF_PEM + h * NT + t] = acc;
    } else {
        if (tid < 184) {
            const int a = tid >> 3, h = tid & 7;
            float acc = 0.f;
            #pragma unroll 8
            for (int ee = 0; ee < NAE; ++ee)
                acc = fmaf(E_var[a * NAE + ee], ws[OFF_VWO + h * NDM + 256 + ee], acc);
            ws[OFF_EVV + tid] = acc;
        }
    }
}

// ---------------- ef: per-(b,a) scores/softmax, LDS-only hot loop ----------------
__global__ __launch_bounds__(256) void ef_kernel(
    const float* __restrict__ data, const int* __restrict__ lengths,
    const float* __restrict__ W_embed, const float* __restrict__ b_embed,
    float* ws)
{
    const int wg = blockIdx.x, tid = threadIdx.x;
    const int a = wg % NA;
    const int L = lengths[wg];
    if (L == 0) { if (tid == 0) ws[OFF_S + wg] = 0.f; return; }

    __shared__ __align__(16) float combo[4096];  // per e: {qk[h0..7], VWo[h0..7]}; reused as sc/mvb/partials
    __shared__ float xs[128];
    __shared__ float2 Wb[256];
    __shared__ float red[4];

    if (tid < 128) xs[tid] = data[wg * NT + tid];
    Wb[tid] = make_float2(W_embed[a * ND + tid], b_embed[a * ND + tid]);
    {
        const float* qkp = ws + OFF_QK + (size_t)wg * 2048;
        #pragma unroll
        for (int k = 0; k < 8; ++k) combo[tid * 16 + k] = qkp[k * 256 + tid];
        #pragma unroll
        for (int k = 0; k < 8; ++k) combo[tid * 16 + 8 + k] = ws[OFF_VWO + k * NDM + tid];
    }
    __syncthreads();

    // relu-part GEMM: zero global loads in the loop
    {
        const int t = tid & 127, half = tid >> 7;
        const float xt = xs[t];
        float accS[8], accM[8];
        #pragma unroll
        for (int h = 0; h < 8; ++h) { accS[h] = 0.f; accM[h] = 0.f; }
        const int ebase = half * 128;
        const float4* comboV = (const float4*)combo + ebase * 4;
        #pragma unroll 2
        for (int ee = 0; ee < 128; ++ee) {
            const float2 wb = Wb[ebase + ee];
            const float m = fmaxf(fmaf(xt, wb.x, wb.y), 0.f);
            const float4 c0 = comboV[ee * 4 + 0];
            const float4 c1 = comboV[ee * 4 + 1];
            const float4 c2 = comboV[ee * 4 + 2];
            const float4 c3 = comboV[ee * 4 + 3];
            accS[0] = fmaf(m, c0.x, accS[0]); accS[1] = fmaf(m, c0.y, accS[1]);
            accS[2] = fmaf(m, c0.z, accS[2]); accS[3] = fmaf(m, c0.w, accS[3]);
            accS[4] = fmaf(m, c1.x, accS[4]); accS[5] = fmaf(m, c1.y, accS[5]);
            accS[6] = fmaf(m, c1.z, accS[6]); accS[7] = fmaf(m, c1.w, accS[7]);
            accM[0] = fmaf(m, c2.x, accM[0]); accM[1] = fmaf(m, c2.y, accM[1]);
            accM[2] = fmaf(m, c2.z, accM[2]); accM[3] = fmaf(m, c2.w, accM[3]);
            accM[4] = fmaf(m, c3.x, accM[4]); accM[5] = fmaf(m, c3.y, accM[5]);
            accM[6] = fmaf(m, c3.z, accM[6]); accM[7] = fmaf(m, c3.w, accM[7]);
        }
        __syncthreads();  // combo reads done -> reuse region
        float* sc   = combo;
        float* mvb  = combo + 1024;
        float* scP1 = combo + 2048;
        float* mvP1 = combo + 3072;
        if (half == 1) {
            #pragma unroll
            for (int h = 0; h < 8; ++h) { scP1[h * 128 + t] = accS[h]; mvP1[h * 128 + t] = accM[h]; }
        }
        __syncthreads();
        if (half == 0) {
            const float* pes = ws + OFF_PES + (size_t)wg * 1024;
            const float* pem = ws + OFF_PEM;
            #pragma unroll
            for (int h = 0; h < 8; ++h) {
                sc[h * 128 + t]  = accS[h] + scP1[h * 128 + t] + pes[h * 128 + t];
                mvb[h * 128 + t] = accM[h] + mvP1[h * 128 + t] + pem[h * 128 + t];
            }
        }
    }
    __syncthreads();

    // per-head softmax over t<L; s_h = sum_t p*(mv+vb)
    {
        const float* sc  = combo;
        const float* mvb = combo + 1024;
        const int wv = tid >> 6, lane = tid & 63;
        float wsum = 0.f;
        for (int hh = 0; hh < 2; ++hh) {
            const int h = wv * 2 + hh;
            float s1 = (lane < L) ? sc[h * 128 + lane] : -3e38f;
            float s2 = (lane + 64 < L) ? sc[h * 128 + 64 + lane] : -3e38f;
            float mx = fmaxf(s1, s2);
            #pragma unroll
            for (int off = 32; off > 0; off >>= 1)
                mx = fmaxf(mx, __shfl_down(mx, off, 64));
            mx = __shfl(mx, 0, 64);
            const float vbv = ws[OFF_EVV + a * 8 + h] + ws[OFF_CST + 8 + h];
            float e1 = (lane < L) ? __expf(s1 - mx) : 0.f;
            float e2 = (lane + 64 < L) ? __expf(s2 - mx) : 0.f;
            float num = e1 * (mvb[h * 128 + lane] + vbv);
            num = fmaf(e2, mvb[h * 128 + 64 + lane] + vbv, num);
            float den = e1 + e2;
            #pragma unroll
            for (int off = 32; off > 0; off >>= 1) {
                num += __shfl_down(num, off, 64);
                den += __shfl_down(den, off, 64);
            }
            if (lane == 0) wsum += num / den;
        }
        if (lane == 0) red[wv] = wsum;
    }
    __syncthreads();
    if (tid == 0)
        ws[OFF_S + wg] = ws[OFF_CST + 7] + red[0] + red[1] + red[2] + red[3];
}

__global__ __launch_bounds__(64) void final_kernel(
    const float* __restrict__ statics, const int* __restrict__ lengths,
    const float* __restrict__ ws, float* __restrict__ out)
{
    const int b = threadIdx.x;
    const float* s_arr = ws + OFF_S;
    const float* cst = ws + OFF_CST;
    float sum = 0.f;
    int n = 0;
    for (int a = 0; a < NA; ++a) {
        if (lengths[b * NA + a] > 0) { sum += s_arr[b * NA + a]; ++n; }
    }
    float o = sum / ((float)n + 1e-9f);
    #pragma unroll
    for (int i = 0; i < NS; ++i)
        o = fmaf(statics[b * NS + i], cst[i], o);
    o += cst[6];
    out[b] = o;
}

extern "C" void kernel_launch(void* const* d_in, const int* in_sizes, int n_in,
                              void* d_out, int out_size, void* d_ws, size_t ws_size,
                              hipStream_t stream) {
    const float* data     = (const float*)d_in[0];
    // d_in[1] = time (implied by mask; unused)
    const int*   mask     = (const int*)d_in[2];
    const float* statics  = (const float*)d_in[3];
    const float* W_embed  = (const float*)d_in[4];
    const float* b_embed  = (const float*)d_in[5];
    const float* E_var    = (const float*)d_in[6];
    const float* W_static = (const float*)d_in[7];
    const float* b_static = (const float*)d_in[8];
    const float* Wq       = (const float*)d_in[9];
    const float* bq       = (const float*)d_in[10];
    const float* Wk       = (const float*)d_in[11];
    // d_in[12] = bk (uniform over t -> cancels in softmax; unused)
    const float* Wv       = (const float*)d_in[13];
    const float* bv       = (const float*)d_in[14];
    const float* Wo       = (const float*)d_in[15];
    const float* bo       = (const float*)d_in[16];
    const float* Wg       = (const float*)d_in[17];
    const float* bg       = (const float*)d_in[18];
    float* out = (float*)d_out;
    float* ws  = (float*)d_ws;

    setup1_kernel<<<dim3(416), dim3(256), 0, stream>>>(Wk, Wq, bq, E_var, Wv, Wo, Wg,
                                                       bv, bo, W_static, b_static, bg, ws);
    proj_kernel<<<dim3(373), dim3(256), 0, stream>>>(data, mask, W_embed, b_embed,
                                                     E_var, Wq, ws);
    ef_kernel<<<dim3(NBA), dim3(256), 0, stream>>>(data, mask, W_embed, b_embed, ws);
    final_kernel<<<dim3(1), dim3(64), 0, stream>>>(statics, mask, ws, out);
}